// Round 2
// baseline (1315.452 us; speedup 1.0000x reference)
//
#include <hip/hip_runtime.h>

#define N_NODES 100000
#define N_EDGES 1600000
#define NODE_IN 64
#define EDGE_OUT 48
#define HID 128
#define MLP_IN 209   // 64 + 3*48 + 1
#define NB 32        // nodes per block in MLP kernel

// ---------------- init: s=0, cnt=0, m=-inf ----------------
__global__ void init_ws(float* __restrict__ s, float* __restrict__ m,
                        float* __restrict__ cnt) {
    int i = blockIdx.x * 256 + threadIdx.x;
    int tot = N_NODES * EDGE_OUT;
    if (i < tot) {
        s[i] = 0.0f;
        ((int*)m)[i] = 0xff800000;  // -inf
    }
    if (i < N_NODES) cnt[i] = 0.0f;
}

// float atomic max via sign-split (positive: int max; negative: uint min)
__device__ __forceinline__ void atomicMaxF(float* addr, float val) {
    if (val >= 0.0f) {
        atomicMax((int*)addr, __float_as_int(val));
    } else {
        atomicMin((unsigned int*)addr, __float_as_uint(val));
    }
}

// ---------------- scatter: one thread per (edge, feature) ----------------
__global__ __launch_bounds__(256) void scatter_edges(
        const float* __restrict__ ea, const int* __restrict__ col,
        float* __restrict__ s, float* __restrict__ m, float* __restrict__ cnt) {
    int i = blockIdx.x * 256 + threadIdx.x;
    if (i >= N_EDGES * EDGE_OUT) return;
    int e = i / EDGE_OUT;
    int f = i - e * EDGE_OUT;
    float v = ea[i];                 // fully coalesced 307MB stream
    int d = col[e];                  // broadcast within 48-thread run (cached)
    atomicAdd(&s[d * EDGE_OUT + f], v);
    atomicMaxF(&m[d * EDGE_OUT + f], v);
    if (f == 0) atomicAdd(&cnt[d], 1.0f);
}

// ---------------- fused MLP: h=[x|s|m|mean|u[batch]]; relu(h@W1+b1)@W2+b2+x ----
__global__ __launch_bounds__(256) void mlp_kernel(
        const float* __restrict__ x, const float* __restrict__ u,
        const int* __restrict__ batch,
        const float* __restrict__ W1, const float* __restrict__ b1,
        const float* __restrict__ W2, const float* __restrict__ b2,
        const float* __restrict__ s, const float* __restrict__ m,
        const float* __restrict__ cnt, float* __restrict__ out) {
    __shared__ float h[NB][MLP_IN + 3];   // 32 x 212 (pad)
    __shared__ float h1[NB][HID + 2];     // 32 x 130 (pad)
    const int t = threadIdx.x;
    const int node0 = blockIdx.x * NB;

    // build h tile: cols [0,64)=x  [64,112)=sum  [112,160)=max  [160,208)=mean  [208]=u[batch]
    for (int i = t; i < NB * MLP_IN; i += 256) {
        int r = i / MLP_IN;
        int c = i - r * MLP_IN;
        int g = node0 + r;
        float v;
        if (c < 64) {
            v = x[g * 64 + c];
        } else if (c < 112) {
            v = s[g * 48 + (c - 64)];
        } else if (c < 160) {
            float mv = m[g * 48 + (c - 112)];
            v = (cnt[g] > 0.0f) ? mv : 0.0f;
        } else if (c < 208) {
            v = s[g * 48 + (c - 160)] / fmaxf(cnt[g], 1.0f);
        } else {
            v = u[batch[g]];
        }
        h[r][c] = v;
    }
    __syncthreads();

    // layer 1: [32,209] @ [209,128]; thread -> 4 cols (j0) x 4 rows (r0)
    {
        const int j0 = (t & 31) * 4;
        const int r0 = (t >> 5) * 4;
        float acc[4][4];
        #pragma unroll
        for (int a = 0; a < 4; a++)
            #pragma unroll
            for (int b = 0; b < 4; b++) acc[a][b] = b1[j0 + b];
        for (int k = 0; k < MLP_IN; k++) {
            float4 w = *(const float4*)&W1[k * HID + j0];
            float hv[4];
            #pragma unroll
            for (int a = 0; a < 4; a++) hv[a] = h[r0 + a][k];
            #pragma unroll
            for (int a = 0; a < 4; a++) {
                acc[a][0] += hv[a] * w.x;
                acc[a][1] += hv[a] * w.y;
                acc[a][2] += hv[a] * w.z;
                acc[a][3] += hv[a] * w.w;
            }
        }
        #pragma unroll
        for (int a = 0; a < 4; a++)
            #pragma unroll
            for (int b = 0; b < 4; b++)
                h1[r0 + a][j0 + b] = fmaxf(acc[a][b], 0.0f);
    }
    __syncthreads();

    // layer 2: [32,128] @ [128,64]; thread -> 4 cols x 2 rows; residual from h cols [0,64)
    {
        const int j0 = (t & 15) * 4;
        const int r0 = (t >> 4) * 2;
        float acc[2][4];
        #pragma unroll
        for (int a = 0; a < 2; a++)
            #pragma unroll
            for (int b = 0; b < 4; b++) acc[a][b] = b2[j0 + b];
        for (int k = 0; k < HID; k++) {
            float4 w = *(const float4*)&W2[k * NODE_IN + j0];
            #pragma unroll
            for (int a = 0; a < 2; a++) {
                float hv = h1[r0 + a][k];
                acc[a][0] += hv * w.x;
                acc[a][1] += hv * w.y;
                acc[a][2] += hv * w.z;
                acc[a][3] += hv * w.w;
            }
        }
        #pragma unroll
        for (int a = 0; a < 2; a++) {
            int g = node0 + r0 + a;
            float4 o;
            o.x = acc[a][0] + h[r0 + a][j0 + 0];
            o.y = acc[a][1] + h[r0 + a][j0 + 1];
            o.z = acc[a][2] + h[r0 + a][j0 + 2];
            o.w = acc[a][3] + h[r0 + a][j0 + 3];
            *(float4*)&out[g * NODE_IN + j0] = o;
        }
    }
}

extern "C" void kernel_launch(void* const* d_in, const int* in_sizes, int n_in,
                              void* d_out, int out_size, void* d_ws, size_t ws_size,
                              hipStream_t stream) {
    const float* x     = (const float*)d_in[0];
    const int*   ei    = (const int*)d_in[1];
    const float* ea    = (const float*)d_in[2];
    const float* u     = (const float*)d_in[3];
    const int*   batch = (const int*)d_in[4];
    const float* W1    = (const float*)d_in[5];
    const float* b1    = (const float*)d_in[6];
    const float* W2    = (const float*)d_in[7];
    const float* b2    = (const float*)d_in[8];
    float* out = (float*)d_out;

    // workspace layout: s [N*48] | m [N*48] | cnt [N]  (38.8 MB)
    float* s   = (float*)d_ws;
    float* m   = s + (size_t)N_NODES * EDGE_OUT;
    float* cnt = m + (size_t)N_NODES * EDGE_OUT;

    const int* col = ei + N_EDGES;   // edge_index row 1 = destination

    int initTot = N_NODES * EDGE_OUT;
    hipLaunchKernelGGL(init_ws, dim3((initTot + 255) / 256), dim3(256), 0, stream,
                       s, m, cnt);

    int scTot = N_EDGES * EDGE_OUT;
    hipLaunchKernelGGL(scatter_edges, dim3((scTot + 255) / 256), dim3(256), 0, stream,
                       ea, col, s, m, cnt);

    hipLaunchKernelGGL(mlp_kernel, dim3(N_NODES / NB), dim3(256), 0, stream,
                       x, u, batch, W1, b1, W2, b2, s, m, cnt, out);
}

// Round 3
// 1208.947 us; speedup vs baseline: 1.0881x; 1.0881x over previous
//
#include <hip/hip_runtime.h>
#include <math.h>

#define N_NODES 100000
#define N_EDGES 1600000
#define NODE_IN 64
#define EDGE_OUT 48
#define HID 128
#define MLP_IN 209      // 64 + 3*48 + 1
#define NB 32           // nodes per MLP block
#define HTS 36          // ht row stride (floats), mult of 4 for b128 alignment
#define H1S 132         // h1 row stride (floats), 128+4

// ---------- 1. zero degree/cursor ----------
__global__ void k_zero(int* __restrict__ cur) {
    int i = blockIdx.x * 256 + threadIdx.x;
    if (i < N_NODES) cur[i] = 0;
}

// ---------- 2. count edges per destination ----------
__global__ __launch_bounds__(256) void k_count(const int* __restrict__ col,
                                               int* __restrict__ cur) {
    int e = blockIdx.x * 256 + threadIdx.x;
    if (e < N_EDGES) atomicAdd(&cur[col[e]], 1);
}

// ---------- 3. exclusive scan (single block) -> off[0..N], cur=off copy ----------
__global__ __launch_bounds__(1024) void k_scan(int* __restrict__ cur,
                                               int* __restrict__ off) {
    __shared__ int part[1024];
    const int t = threadIdx.x;
    const int CH = (N_NODES + 1023) / 1024;   // 98
    const int base = t * CH;
    int sum = 0;
    for (int i = 0; i < CH; i++) {
        int idx = base + i;
        if (idx < N_NODES) sum += cur[idx];
    }
    part[t] = sum;
    __syncthreads();
    for (int o = 1; o < 1024; o <<= 1) {
        int v = 0;
        if (t >= o) v = part[t - o];
        __syncthreads();
        part[t] += v;
        __syncthreads();
    }
    int run = part[t] - sum;                  // exclusive prefix of this chunk
    for (int i = 0; i < CH; i++) {
        int idx = base + i;
        if (idx < N_NODES) {
            int d = cur[idx];
            off[idx] = run;
            cur[idx] = run;                   // cursor for fill
            run += d;
        }
    }
    if (t == 1023) off[N_NODES] = run;        // total
}

// ---------- 4. fill CSR edge-id list ----------
__global__ __launch_bounds__(256) void k_fill(const int* __restrict__ col,
                                              int* __restrict__ cur,
                                              int* __restrict__ eix) {
    int e = blockIdx.x * 256 + threadIdx.x;
    if (e < N_EDGES) {
        int pos = atomicAdd(&cur[col[e]], 1);
        eix[pos] = e;
    }
}

// ---------- 5. fused gather + MLP ----------
// h layout (transposed in LDS): ht[k][r], k=0..208, r=0..31, stride HTS
//   k in [0,64)   : x
//   k in [64,112) : sum
//   k in [112,160): max (0 if empty)
//   k in [160,208): mean
//   k == 208      : u[batch]
__global__ __launch_bounds__(256) void k_mlp(
        const float* __restrict__ x, const float* __restrict__ ea,
        const float* __restrict__ u, const int* __restrict__ batch,
        const float* __restrict__ W1, const float* __restrict__ b1,
        const float* __restrict__ W2, const float* __restrict__ b2,
        const int* __restrict__ off, const int* __restrict__ eix,
        float* __restrict__ out) {
    __shared__ float ht[MLP_IN * HTS];        // 209*36*4 = 30.1 KB
    __shared__ float h1[NB * H1S];            // 32*132*4 = 16.9 KB
    const int t = threadIdx.x;
    const int node0 = blockIdx.x * NB;

    // --- load x (transposed into ht) ---
    for (int i = t; i < NB * NODE_IN; i += 256) {
        int r = i >> 6, c = i & 63;           // wave reads one x row: coalesced
        ht[c * HTS + r] = x[(node0 + r) * NODE_IN + c];
    }
    // --- u[batch] row ---
    if (t < NB) ht[208 * HTS + t] = u[batch[node0 + t]];

    // --- gather edges: wave wv handles nodes [wv*8, wv*8+8) ---
    {
        const int wv = t >> 6;
        const int lane = t & 63;
        const int f = lane & 15;              // feature 0..15 (x3 regs -> 48)
        const int g = lane >> 4;              // edge slot 0..3
        for (int i = 0; i < 8; i++) {
            const int r = wv * 8 + i;
            const int n = node0 + r;
            const int beg = off[n], end = off[n + 1];
            float s0 = 0.f, s1 = 0.f, s2 = 0.f;
            float m0 = -INFINITY, m1 = -INFINITY, m2 = -INFINITY;
            for (int p = beg + g; p < end; p += 4) {
                const int e = eix[p];
                const float* row = ea + (size_t)e * EDGE_OUT;
                float v0 = row[f];
                float v1 = row[f + 16];
                float v2 = row[f + 32];
                s0 += v0; s1 += v1; s2 += v2;
                m0 = fmaxf(m0, v0); m1 = fmaxf(m1, v1); m2 = fmaxf(m2, v2);
            }
            // butterfly over the 4 edge-slot groups (xor 16, 32)
            #pragma unroll
            for (int d = 16; d < 64; d <<= 1) {
                s0 += __shfl_xor(s0, d); s1 += __shfl_xor(s1, d); s2 += __shfl_xor(s2, d);
                m0 = fmaxf(m0, __shfl_xor(m0, d));
                m1 = fmaxf(m1, __shfl_xor(m1, d));
                m2 = fmaxf(m2, __shfl_xor(m2, d));
            }
            const int deg = end - beg;
            if (lane < 16) {
                const float fd = fmaxf((float)deg, 1.0f);
                ht[(64 + f) * HTS + r] = s0;
                ht[(64 + f + 16) * HTS + r] = s1;
                ht[(64 + f + 32) * HTS + r] = s2;
                ht[(112 + f) * HTS + r] = (deg > 0) ? m0 : 0.f;
                ht[(112 + f + 16) * HTS + r] = (deg > 0) ? m1 : 0.f;
                ht[(112 + f + 32) * HTS + r] = (deg > 0) ? m2 : 0.f;
                ht[(160 + f) * HTS + r] = s0 / fd;
                ht[(160 + f + 16) * HTS + r] = s1 / fd;
                ht[(160 + f + 32) * HTS + r] = s2 / fd;
            }
        }
    }
    __syncthreads();

    // --- layer 1: [32,209] @ [209,128] -> relu -> h1[32][128] ---
    {
        const int j0 = (t & 31) * 4;          // output col group
        const int r0 = (t >> 5) * 4;          // output row group
        float acc[4][4];
        #pragma unroll
        for (int a = 0; a < 4; a++)
            #pragma unroll
            for (int b = 0; b < 4; b++) acc[a][b] = b1[j0 + b];
        #pragma unroll 4
        for (int k = 0; k < MLP_IN; k++) {
            const float4 w = *(const float4*)&W1[k * HID + j0];
            const float4 hv = *(const float4*)&ht[k * HTS + r0];
            acc[0][0] += hv.x * w.x; acc[0][1] += hv.x * w.y; acc[0][2] += hv.x * w.z; acc[0][3] += hv.x * w.w;
            acc[1][0] += hv.y * w.x; acc[1][1] += hv.y * w.y; acc[1][2] += hv.y * w.z; acc[1][3] += hv.y * w.w;
            acc[2][0] += hv.z * w.x; acc[2][1] += hv.z * w.y; acc[2][2] += hv.z * w.z; acc[2][3] += hv.z * w.w;
            acc[3][0] += hv.w * w.x; acc[3][1] += hv.w * w.y; acc[3][2] += hv.w * w.z; acc[3][3] += hv.w * w.w;
        }
        #pragma unroll
        for (int a = 0; a < 4; a++)
            #pragma unroll
            for (int b = 0; b < 4; b++)
                h1[(r0 + a) * H1S + j0 + b] = fmaxf(acc[a][b], 0.f);
    }
    __syncthreads();

    // --- layer 2: [32,128] @ [128,64] + b2 + residual(x) -> out ---
    {
        const int j0 = (t & 15) * 4;          // output col group (64 cols)
        const int r0 = (t >> 4) * 2;          // output row group (32 rows)
        float acc[2][4];
        #pragma unroll
        for (int a = 0; a < 2; a++)
            #pragma unroll
            for (int b = 0; b < 4; b++) acc[a][b] = b2[j0 + b];
        #pragma unroll
        for (int k4 = 0; k4 < HID; k4 += 4) {
            float4 h0 = *(const float4*)&h1[r0 * H1S + k4];
            float4 h1v = *(const float4*)&h1[(r0 + 1) * H1S + k4];
            #pragma unroll
            for (int q = 0; q < 4; q++) {
                const float4 w = *(const float4*)&W2[(k4 + q) * NODE_IN + j0];
                const float ha = (q == 0) ? h0.x : (q == 1) ? h0.y : (q == 2) ? h0.z : h0.w;
                const float hb = (q == 0) ? h1v.x : (q == 1) ? h1v.y : (q == 2) ? h1v.z : h1v.w;
                acc[0][0] += ha * w.x; acc[0][1] += ha * w.y; acc[0][2] += ha * w.z; acc[0][3] += ha * w.w;
                acc[1][0] += hb * w.x; acc[1][1] += hb * w.y; acc[1][2] += hb * w.z; acc[1][3] += hb * w.w;
            }
        }
        #pragma unroll
        for (int a = 0; a < 2; a++) {
            const int r = r0 + a;
            float4 o;
            o.x = acc[a][0] + ht[(j0 + 0) * HTS + r];
            o.y = acc[a][1] + ht[(j0 + 1) * HTS + r];
            o.z = acc[a][2] + ht[(j0 + 2) * HTS + r];
            o.w = acc[a][3] + ht[(j0 + 3) * HTS + r];
            *(float4*)&out[(size_t)(node0 + r) * NODE_IN + j0] = o;
        }
    }
}

extern "C" void kernel_launch(void* const* d_in, const int* in_sizes, int n_in,
                              void* d_out, int out_size, void* d_ws, size_t ws_size,
                              hipStream_t stream) {
    const float* x     = (const float*)d_in[0];
    const int*   ei    = (const int*)d_in[1];
    const float* ea    = (const float*)d_in[2];
    const float* u     = (const float*)d_in[3];
    const int*   batch = (const int*)d_in[4];
    const float* W1    = (const float*)d_in[5];
    const float* b1    = (const float*)d_in[6];
    const float* W2    = (const float*)d_in[7];
    const float* b2    = (const float*)d_in[8];
    float* out = (float*)d_out;

    // workspace: off [N+1] | cur [N] | eix [E]   (~7.2 MB)
    int* off = (int*)d_ws;
    int* cur = off + (N_NODES + 1);
    int* eix = cur + N_NODES;

    const int* col = ei + N_EDGES;            // destination node per edge

    hipLaunchKernelGGL(k_zero, dim3((N_NODES + 255) / 256), dim3(256), 0, stream, cur);
    hipLaunchKernelGGL(k_count, dim3((N_EDGES + 255) / 256), dim3(256), 0, stream, col, cur);
    hipLaunchKernelGGL(k_scan, dim3(1), dim3(1024), 0, stream, cur, off);
    hipLaunchKernelGGL(k_fill, dim3((N_EDGES + 255) / 256), dim3(256), 0, stream, col, cur, eix);
    hipLaunchKernelGGL(k_mlp, dim3(N_NODES / NB), dim3(256), 0, stream,
                       x, ea, u, batch, W1, b1, W2, b2, off, eix, out);
}